// Round 10
// baseline (294.555 us; speedup 1.0000x reference)
//
#include <hip/hip_runtime.h>

#define N_NODES 100000
#define N_EDGES 1600000
#define NODE_DIM 24
#define HIDDEN 128
#define BSHIFT 9     // 512 nodes per bucket
#define NBUCK 196    // ceil(100000/512)
#define BCAP 10240   // per-bucket tmp capacity (mean 8163, +23 sigma)
#define P1_EDGES 2048
#define TILE 32      // nodes per conv block (100000 % 32 == 0)
#define LREC 1024    // staged CSR records per block (mean 512, +22 sigma)
#define NI_BLOCKS 2048

typedef __attribute__((ext_vector_type(8))) short bf16x8;
typedef __attribute__((ext_vector_type(4))) float f32x4;

template <int N> struct IC { static constexpr int value = N; };

__device__ __forceinline__ ushort f2bf(float f) {
  uint u = __builtin_bit_cast(uint, f);
  u += 0x7fffu + ((u >> 16) & 1u);  // RTNE
  return (ushort)(u >> 16);
}
__device__ __forceinline__ float bflo(uint v) { return __builtin_bit_cast(float, v << 16); }
__device__ __forceinline__ float bfhi(uint v) { return __builtin_bit_cast(float, v & 0xffff0000u); }

// ---------------------------------------------------------------------------
// prep: blocks [0,NI_BLOCKS): h0 = x@W_in+b_in -> bf16 table (dword stores)
//       blocks [NI_BLOCKS, NI_BLOCKS+64): W1t/W2t[n][k] = bf16(W[k][n])
//       block NI_BLOCKS+64: zero gcur
// ---------------------------------------------------------------------------
__global__ __launch_bounds__(256) void prep_kernel(
    const float* __restrict__ x, const float* __restrict__ W_in,
    const float* __restrict__ b_in, const float* __restrict__ W1,
    const float* __restrict__ W2, uint* __restrict__ hb32,
    ushort* __restrict__ W1t, ushort* __restrict__ W2t,
    int* __restrict__ gcur) {
  if (blockIdx.x >= NI_BLOCKS) {
    const int bx = blockIdx.x - NI_BLOCKS;
    if (bx >= 64) {  // gcur zeroing
      if (threadIdx.x < NBUCK) gcur[threadIdx.x] = 0;
      return;
    }
    const int i = bx * 256 + threadIdx.x;  // weight transpose+cast
    if (i < HIDDEN * HIDDEN) {
      const int k = i >> 7, n = i & 127;
      W1t[n * HIDDEN + k] = f2bf(W1[k * HIDDEN + n]);
      W2t[n * HIDDEN + k] = f2bf(W2[k * HIDDEN + n]);
    }
    return;
  }
  __shared__ float w_lds[NODE_DIM * HIDDEN];
  __shared__ float b_lds[HIDDEN];
  for (int i = threadIdx.x; i < NODE_DIM * HIDDEN; i += 256) w_lds[i] = W_in[i];
  if (threadIdx.x < HIDDEN) b_lds[threadIdx.x] = b_in[threadIdx.x];
  __syncthreads();
  const int l = threadIdx.x & 63;
  const int g = threadIdx.x >> 6;
  const int j0 = l * 2;
  for (int n = blockIdx.x * 4 + g; n < N_NODES; n += NI_BLOCKS * 4) {
    float a0 = b_lds[j0], a1 = b_lds[j0 + 1];
    const float* xr = x + (size_t)n * NODE_DIM;
#pragma unroll
    for (int d = 0; d < NODE_DIM; ++d) {
      const float xv = xr[d];
      a0 = fmaf(xv, w_lds[d * HIDDEN + j0], a0);
      a1 = fmaf(xv, w_lds[d * HIDDEN + j0 + 1], a1);
    }
    hb32[(size_t)n * 64 + l] = (uint)f2bf(a0) | ((uint)f2bf(a1) << 16);
  }
}

// ---------------------------------------------------------------------------
// Phase 1: bucket scatter into fixed-capacity per-bucket regions.
// ---------------------------------------------------------------------------
__global__ __launch_bounds__(256) void k_bucket_scatter(
    const int* __restrict__ srcs, const int* __restrict__ dsts,
    const float2* __restrict__ ea2, int* __restrict__ gcur,
    uint2* __restrict__ tmp) {
  __shared__ int hist[256];
  __shared__ int sc[256];
  __shared__ int lofs[256];
  __shared__ int base[256];
  __shared__ int cur2[256];
  __shared__ uint2 stage[P1_EDGES];
  __shared__ uchar stage_b[P1_EDGES];
  const int t = threadIdx.x;
  const int e0 = blockIdx.x * P1_EDGES;

  hist[t] = 0;
  cur2[t] = 0;
  __syncthreads();

  uint rw0[8], rw1[8];
  int rb[8];
#pragma unroll
  for (int i = 0; i < 8; ++i) {
    const int e = e0 + t + i * 256;
    if (e < N_EDGES) {
      const int s = srcs[e];
      const int d = dsts[e];
      const float2 a = ea2[e];
      const int b = d >> BSHIFT;
      rb[i] = b;
      rw0[i] = (uint)s | ((uint)(d & 511) << 20);
      rw1[i] = (uint)f2bf(a.x) | ((uint)f2bf(a.y) << 16);
      atomicAdd(&hist[b], 1);
    } else {
      rb[i] = -1;
    }
  }
  __syncthreads();

  int v = hist[t];
  sc[t] = v;
  __syncthreads();
  for (int d = 1; d < 256; d <<= 1) {
    int x = (t >= d) ? sc[t - d] : 0;
    __syncthreads();
    sc[t] += x;
    __syncthreads();
  }
  lofs[t] = sc[t] - v;
  base[t] = (t < NBUCK && v > 0) ? atomicAdd(&gcur[t], v) : 0;
  __syncthreads();

#pragma unroll
  for (int i = 0; i < 8; ++i) {
    if (rb[i] >= 0) {
      const int l = atomicAdd(&cur2[rb[i]], 1);
      const int slot = lofs[rb[i]] + l;
      stage[slot] = make_uint2(rw0[i], rw1[i]);
      stage_b[slot] = (uchar)rb[i];
    }
  }
  __syncthreads();

  const int total = (N_EDGES - e0 < P1_EDGES) ? (N_EDGES - e0) : P1_EDGES;
  for (int s = t; s < total; s += 256) {
    const int b = stage_b[s];
    const int idx = base[b] + (s - lofs[b]);
    if (idx < BCAP) tmp[(size_t)b * BCAP + idx] = stage[s];
  }
}

// ---------------------------------------------------------------------------
// Phase 2: per-bucket. Redundant in-block scan of the 196 bucket counts,
// local histogram + scan -> off[], counting sort -> rec.
// ---------------------------------------------------------------------------
__global__ __launch_bounds__(256) void k_bucket_sort(
    const uint2* __restrict__ tmp, const int* __restrict__ gcur,
    int* __restrict__ off, uint2* __restrict__ rec) {
  __shared__ int gsc[256];
  __shared__ int lcnt[512];
  __shared__ int lofs[512];
  __shared__ int lcur[512];
  __shared__ int psc[256];
  const int t = threadIdx.x;
  const int b = blockIdx.x;
  const int nb0 = b << BSHIFT;
  const uint2* __restrict__ btmp = tmp + (size_t)b * BCAP;

  const int gv = (t < NBUCK) ? gcur[t] : 0;
  gsc[t] = gv;
  lcnt[t] = 0;
  lcnt[t + 256] = 0;
  __syncthreads();
  for (int d = 1; d < 256; d <<= 1) {
    int x = (t >= d) ? gsc[t - d] : 0;
    __syncthreads();
    gsc[t] += x;
    __syncthreads();
  }
  const int rawcnt = gcur[b];
  const int base = gsc[b] - rawcnt;  // exclusive prefix
  int cnt = rawcnt;
  if (cnt > BCAP) cnt = BCAP;
  if (b == 0 && t == 0) off[N_NODES] = N_EDGES;

  for (int s = t; s < cnt; s += 256) {
    atomicAdd(&lcnt[(btmp[s].x >> 20) & 511], 1);
  }
  __syncthreads();
  const int a0 = lcnt[2 * t], a1 = lcnt[2 * t + 1];
  const int p = a0 + a1;
  psc[t] = p;
  __syncthreads();
  for (int d = 1; d < 256; d <<= 1) {
    int x = (t >= d) ? psc[t - d] : 0;
    __syncthreads();
    psc[t] += x;
    __syncthreads();
  }
  const int ep = psc[t] - p;
  lofs[2 * t] = ep;
  lofs[2 * t + 1] = ep + a0;
  lcur[2 * t] = ep;
  lcur[2 * t + 1] = ep + a0;
  __syncthreads();
  for (int i = t; i < 512; i += 256) {
    const int n = nb0 + i;
    if (n < N_NODES) off[n] = base + lofs[i];
  }
  for (int s = t; s < cnt; s += 256) {
    const uint2 r = btmp[s];
    const int dl = (r.x >> 20) & 511;
    const int pp = atomicAdd(&lcur[dl], 1);
    rec[base + pp] = make_uint2(r.x & 0xFFFFFu, r.y);
  }
}

// ---------------------------------------------------------------------------
// Fused conv, TILE=32 (3125 blocks). Gather: 4 groups of 16 lanes, one 256B
// row per group-load; main loop 3 chunks deep (3 independent row loads in
// flight) under a hard 64-VGPR cap (launch_bounds min-waves=8) so occupancy
// stays at 8 waves/SIMD. shfl_xor reduce; cvt_pk pack; MFMA 2-layer MLP.
// ---------------------------------------------------------------------------
__global__ __launch_bounds__(256, 8) void conv_fused(
    const int* __restrict__ off, const uint2* __restrict__ rec,
    const float* __restrict__ W_e, const float* __restrict__ b_e,
    const uint4* __restrict__ hb4, const ushort* __restrict__ W1t,
    const ushort* __restrict__ W2t, const float* __restrict__ bias1,
    const float* __restrict__ bias2, float* __restrict__ outf,
    ushort* __restrict__ outb, const int relu_out) {
  __shared__ short zs[TILE][136];
  __shared__ uint2 lrec[LREC];
  __shared__ int loff[TILE + 1];
  const int tid = threadIdx.x;
  const int lane = tid & 63;
  const int wave = tid >> 6;
  const int l15 = lane & 15;
  const int grp = lane >> 4;  // 0..3: which edge of the chunk
  const int n0 = blockIdx.x * TILE;

  if (tid <= TILE) loff[tid] = off[n0 + tid];
  const int rbase = off[n0];
  const int rend = off[n0 + TILE];
  const int rcnt = rend - rbase;
  const bool staged = (rcnt <= LREC);
  if (staged) {
    for (int i = tid; i < rcnt; i += 256) lrec[i] = rec[rbase + i];
  }

  // this lane's feature octet weights
  const int j0 = l15 * 8;
  float we0[8], we1[8], beq[8];
#pragma unroll
  for (int k = 0; k < 8; ++k) {
    we0[k] = W_e[j0 + k];
    we1[k] = W_e[HIDDEN + j0 + k];
    beq[k] = b_e[j0 + k];
  }
  __syncthreads();

  // ---- gather phase ----
  {
    auto gather = [&](auto readrec) {
      for (int i = 0; i < 8; ++i) {
        const int n = n0 + wave * 8 + i;
        float acc[8];
#pragma unroll
        for (int k = 0; k < 8; ++k) acc[k] = 0.f;
        const int o = loff[wave * 8 + i] - rbase;
        const int dn = loff[wave * 8 + i + 1] - loff[wave * 8 + i];
        const int nfull = dn >> 2;

        auto edge_math = [&](uint2 r, uint4 hv) {
          const float ex = bflo(r.y), ey = bfhi(r.y);
          const uint hw[4] = {hv.x, hv.y, hv.z, hv.w};
#pragma unroll
          for (int k = 0; k < 4; ++k) {
            const float c0 = fmaf(ex, we0[2 * k], fmaf(ey, we1[2 * k], beq[2 * k]));
            const float c1 = fmaf(ex, we0[2 * k + 1], fmaf(ey, we1[2 * k + 1], beq[2 * k + 1]));
            acc[2 * k] += fmaxf(bflo(hw[k]) + c0, 0.f);
            acc[2 * k + 1] += fmaxf(bfhi(hw[k]) + c1, 0.f);
          }
        };
        auto do_chunks = [&](int obase, auto cn) {
          constexpr int C = decltype(cn)::value;
          uint2 r[C];
          uint4 hv[C];
#pragma unroll
          for (int q = 0; q < C; ++q) r[q] = readrec(obase + q * 4 + grp);
#pragma unroll
          for (int q = 0; q < C; ++q) hv[q] = hb4[(size_t)r[q].x * 16 + l15];
#pragma unroll
          for (int q = 0; q < C; ++q) edge_math(r[q], hv[q]);
        };

        int c = 0;
        for (; c + 3 <= nfull; c += 3) do_chunks(o + c * 4, IC<3>{});
        if (c + 2 <= nfull) { do_chunks(o + c * 4, IC<2>{}); c += 2; }
        if (c < nfull) { do_chunks(o + c * 4, IC<1>{}); c += 1; }
        const int ntail = dn & 3;
        if (grp < ntail) {  // 16-lane-uniform predicate
          const uint2 r0 = readrec(o + nfull * 4 + grp);
          const uint4 hv0 = hb4[(size_t)r0.x * 16 + l15];
          edge_math(r0, hv0);
        }

        // cross-group reduce (4 partials -> replicated total)
#pragma unroll
        for (int k = 0; k < 8; ++k) {
          float v = acc[k];
          v += __shfl_xor(v, 16, 64);
          v += __shfl_xor(v, 32, 64);
          acc[k] = v;
        }
        // self term (no relu, no edge coef)
        const uint4 hs = hb4[(size_t)n * 16 + l15];
        acc[0] += bflo(hs.x); acc[1] += bfhi(hs.x);
        acc[2] += bflo(hs.y); acc[3] += bfhi(hs.y);
        acc[4] += bflo(hs.z); acc[5] += bfhi(hs.z);
        acc[6] += bflo(hs.w); acc[7] += bfhi(hs.w);

        uint p0, p1, p2, p3;
        asm("v_cvt_pk_bf16_f32 %0, %1, %2" : "=v"(p0) : "v"(acc[0]), "v"(acc[1]));
        asm("v_cvt_pk_bf16_f32 %0, %1, %2" : "=v"(p1) : "v"(acc[2]), "v"(acc[3]));
        asm("v_cvt_pk_bf16_f32 %0, %1, %2" : "=v"(p2) : "v"(acc[4]), "v"(acc[5]));
        asm("v_cvt_pk_bf16_f32 %0, %1, %2" : "=v"(p3) : "v"(acc[6]), "v"(acc[7]));
        if (grp == 0) {
          *(uint4*)&zs[wave * 8 + i][l15 * 8] = make_uint4(p0, p1, p2, p3);
        }
      }
    };
    if (staged) {
      gather([&](int i) -> uint2 { return lrec[i]; });
    } else {
      gather([&](int i) -> uint2 { return rec[rbase + i]; });
    }
  }
  __syncthreads();

  // ---- MLP phase (MFMA), 32 rows; z/t aliased in zs ----
  const int kq = grp;
  const int colbase = wave * 32;
  const int c0 = colbase + l15, c1 = colbase + 16 + l15;

  f32x4 acc[2][2];
  {
    const float bb0 = bias1[c0], bb1 = bias1[c1];
#pragma unroll
    for (int mt = 0; mt < 2; ++mt) {
      acc[mt][0] = (f32x4){bb0, bb0, bb0, bb0};
      acc[mt][1] = (f32x4){bb1, bb1, bb1, bb1};
    }
  }
#pragma unroll
  for (int kt = 0; kt < 4; ++kt) {
    const int kk = kt * 32 + kq * 8;
    const bf16x8 bf0 = *(const bf16x8*)&W1t[(size_t)c0 * HIDDEN + kk];
    const bf16x8 bf1 = *(const bf16x8*)&W1t[(size_t)c1 * HIDDEN + kk];
#pragma unroll
    for (int mt = 0; mt < 2; ++mt) {
      const bf16x8 a = *(const bf16x8*)&zs[mt * 16 + l15][kk];
      acc[mt][0] = __builtin_amdgcn_mfma_f32_16x16x32_bf16(a, bf0, acc[mt][0], 0, 0, 0);
      acc[mt][1] = __builtin_amdgcn_mfma_f32_16x16x32_bf16(a, bf1, acc[mt][1], 0, 0, 0);
    }
  }
  __syncthreads();  // all layer-1 reads of zs complete
#pragma unroll
  for (int mt = 0; mt < 2; ++mt)
#pragma unroll
    for (int nt = 0; nt < 2; ++nt)
#pragma unroll
      for (int r = 0; r < 4; ++r) {
        const int row = mt * 16 + kq * 4 + r;
        const int col = colbase + nt * 16 + l15;
        float v = acc[mt][nt][r];
        zs[row][col] = (short)f2bf(v > 0.f ? v : 0.f);
      }
  __syncthreads();

  {
    const float bb0 = bias2[c0], bb1 = bias2[c1];
#pragma unroll
    for (int mt = 0; mt < 2; ++mt) {
      acc[mt][0] = (f32x4){bb0, bb0, bb0, bb0};
      acc[mt][1] = (f32x4){bb1, bb1, bb1, bb1};
    }
  }
#pragma unroll
  for (int kt = 0; kt < 4; ++kt) {
    const int kk = kt * 32 + kq * 8;
    const bf16x8 bf0 = *(const bf16x8*)&W2t[(size_t)c0 * HIDDEN + kk];
    const bf16x8 bf1 = *(const bf16x8*)&W2t[(size_t)c1 * HIDDEN + kk];
#pragma unroll
    for (int mt = 0; mt < 2; ++mt) {
      const bf16x8 a = *(const bf16x8*)&zs[mt * 16 + l15][kk];
      acc[mt][0] = __builtin_amdgcn_mfma_f32_16x16x32_bf16(a, bf0, acc[mt][0], 0, 0, 0);
      acc[mt][1] = __builtin_amdgcn_mfma_f32_16x16x32_bf16(a, bf1, acc[mt][1], 0, 0, 0);
    }
  }
#pragma unroll
  for (int mt = 0; mt < 2; ++mt)
#pragma unroll
    for (int nt = 0; nt < 2; ++nt)
#pragma unroll
      for (int r = 0; r < 4; ++r) {
        const int row = mt * 16 + kq * 4 + r;
        const int col = colbase + nt * 16 + l15;
        float v = acc[mt][nt][r];
        if (relu_out) v = v > 0.f ? v : 0.f;
        if (outf) outf[(size_t)(n0 + row) * HIDDEN + col] = v;
        if (outb) outb[(size_t)(n0 + row) * HIDDEN + col] = f2bf(v);
      }
}

// ---------------------------------------------------------------------------
// Fallback path (atomic scatter + f32 MLP), used only if ws too small
// ---------------------------------------------------------------------------
__global__ __launch_bounds__(256) void node_init_f32(
    const float* __restrict__ x, const float* __restrict__ W_in,
    const float* __restrict__ b_in, float* __restrict__ h) {
  __shared__ float w_lds[NODE_DIM * HIDDEN];
  __shared__ float b_lds[HIDDEN];
  for (int i = threadIdx.x; i < NODE_DIM * HIDDEN; i += 256) w_lds[i] = W_in[i];
  if (threadIdx.x < HIDDEN) b_lds[threadIdx.x] = b_in[threadIdx.x];
  __syncthreads();
  const int j = threadIdx.x & 127;
  const int g = threadIdx.x >> 7;
  for (int n = blockIdx.x * 2 + g; n < N_NODES; n += gridDim.x * 2) {
    float acc = b_lds[j];
    const float* xr = x + (size_t)n * NODE_DIM;
#pragma unroll
    for (int d = 0; d < NODE_DIM; ++d) acc = fmaf(xr[d], w_lds[d * HIDDEN + j], acc);
    h[(size_t)n * HIDDEN + j] = acc;
  }
}

__global__ __launch_bounds__(256) void edge_scatter_kernel(
    const int* __restrict__ ei, const float* __restrict__ ea,
    const float* __restrict__ W_e, const float* __restrict__ b_e,
    const float* __restrict__ h, float* __restrict__ agg) {
  const int j = threadIdx.x & 127;
  const int g = threadIdx.x >> 7;
  const float we0 = W_e[j];
  const float we1 = W_e[HIDDEN + j];
  const float be = b_e[j];
  const int* __restrict__ srcs = ei;
  const int* __restrict__ dsts = ei + N_EDGES;
  const float2* __restrict__ ea2 = (const float2*)ea;
  for (int e = blockIdx.x * 2 + g; e < N_EDGES; e += gridDim.x * 2) {
    const int s = srcs[e];
    const int d = dsts[e];
    const float2 a = ea2[e];
    float m = h[(size_t)s * HIDDEN + j] + fmaf(a.x, we0, fmaf(a.y, we1, be));
    m = m > 0.f ? m : 0.f;
    unsafeAtomicAdd(&agg[(size_t)d * HIDDEN + j], m);
  }
}

template <bool RELU_OUT>
__global__ __launch_bounds__(256) void mlp_f32_kernel(
    const float* __restrict__ zbuf, const float* __restrict__ agg,
    const float* __restrict__ W1, const float* __restrict__ b1,
    const float* __restrict__ W2, const float* __restrict__ b2,
    float* __restrict__ out) {
  const int NB = 32;
  const int NT = 16;
  __shared__ float zs[NB][HIDDEN];
  __shared__ float ts[NB][HIDDEN];
  const int j = threadIdx.x & 127;
  const int g = threadIdx.x >> 7;
  const int n0 = blockIdx.x * NB;

#pragma unroll
  for (int n = 0; n < NT; ++n) {
    const int nn = g * NT + n;
    zs[nn][j] = zbuf[(size_t)(n0 + nn) * HIDDEN + j] + agg[(size_t)(n0 + nn) * HIDDEN + j];
  }
  __syncthreads();

  float acc[NT];
  const float b1j = b1[j];
#pragma unroll
  for (int n = 0; n < NT; ++n) acc[n] = b1j;
  for (int k = 0; k < HIDDEN; k += 4) {
    const float w0 = W1[(k + 0) * HIDDEN + j];
    const float w1 = W1[(k + 1) * HIDDEN + j];
    const float w2 = W1[(k + 2) * HIDDEN + j];
    const float w3 = W1[(k + 3) * HIDDEN + j];
#pragma unroll
    for (int n = 0; n < NT; ++n) {
      const float4 z = *reinterpret_cast<const float4*>(&zs[g * NT + n][k]);
      acc[n] = fmaf(z.x, w0, acc[n]);
      acc[n] = fmaf(z.y, w1, acc[n]);
      acc[n] = fmaf(z.z, w2, acc[n]);
      acc[n] = fmaf(z.w, w3, acc[n]);
    }
  }
#pragma unroll
  for (int n = 0; n < NT; ++n) ts[g * NT + n][j] = acc[n] > 0.f ? acc[n] : 0.f;
  __syncthreads();

  const float b2j = b2[j];
#pragma unroll
  for (int n = 0; n < NT; ++n) acc[n] = b2j;
  for (int k = 0; k < HIDDEN; k += 4) {
    const float w0 = W2[(k + 0) * HIDDEN + j];
    const float w1 = W2[(k + 1) * HIDDEN + j];
    const float w2 = W2[(k + 2) * HIDDEN + j];
    const float w3 = W2[(k + 3) * HIDDEN + j];
#pragma unroll
    for (int n = 0; n < NT; ++n) {
      const float4 z = *reinterpret_cast<const float4*>(&ts[g * NT + n][k]);
      acc[n] = fmaf(z.x, w0, acc[n]);
      acc[n] = fmaf(z.y, w1, acc[n]);
      acc[n] = fmaf(z.z, w2, acc[n]);
      acc[n] = fmaf(z.w, w3, acc[n]);
    }
  }
#pragma unroll
  for (int n = 0; n < NT; ++n) {
    float v = acc[n];
    if (RELU_OUT) v = v > 0.f ? v : 0.f;
    out[(size_t)(n0 + g * NT + n) * HIDDEN + j] = v;
  }
}

extern "C" void kernel_launch(void* const* d_in, const int* in_sizes, int n_in,
                              void* d_out, int out_size, void* d_ws, size_t ws_size,
                              hipStream_t stream) {
  const float* x    = (const float*)d_in[0];
  const int*   ei   = (const int*)d_in[1];
  const float* ea   = (const float*)d_in[2];
  const float* W_in = (const float*)d_in[3];
  const float* b_in = (const float*)d_in[4];
  const float* W_e  = (const float*)d_in[5];
  const float* b_e  = (const float*)d_in[6];
  const float* W1   = (const float*)d_in[7];
  const float* b1   = (const float*)d_in[8];
  const float* W2   = (const float*)d_in[9];
  const float* b2   = (const float*)d_in[10];

  const int* srcs = ei;
  const int* dsts = ei + N_EDGES;
  const float2* ea2 = (const float2*)ea;

  float* h = (float*)d_out;  // final f32 output
  char* ws = (char*)d_ws;

  // ws layout. tmp (phase-1 buckets) overlays hb_b (tmp dead after sort).
  const size_t OFF_OFF  = 0;                       // (N+1)*4 = 400004
  const size_t GCUR_OFF = 402432;                  // 784
  const size_t WT1_OFF  = 410624;                  // 32768
  const size_t WT2_OFF  = 443392;                  // 32768
  const size_t REC_OFF  = 1048576;                 // 12.8 MB final CSR records
  const size_t HBA_OFF  = REC_OFF + 12800000;      // 25.6 MB bf16 h (table A)
  const size_t TMP_OFF  = HBA_OFF + 25600000;      // 16.06 MB bucket regions
  const size_t HBB_OFF  = TMP_OFF;                 // 25.6 MB bf16 h (table B)
  const size_t need = HBB_OFF + 25600000;          // ~65.0 MB

  if (ws_size >= need) {
    int* off     = (int*)(ws + OFF_OFF);
    int* gcur    = (int*)(ws + GCUR_OFF);
    ushort* W1t  = (ushort*)(ws + WT1_OFF);
    ushort* W2t  = (ushort*)(ws + WT2_OFF);
    uint2* rec   = (uint2*)(ws + REC_OFF);
    ushort* hba  = (ushort*)(ws + HBA_OFF);
    uint2* tmp   = (uint2*)(ws + TMP_OFF);
    ushort* hbb  = (ushort*)(ws + HBB_OFF);

    // h0 -> bf16 table; W1t/W2t transpose; gcur zero (merged kernel)
    prep_kernel<<<NI_BLOCKS + 65, 256, 0, stream>>>(x, W_in, b_in, W1, W2,
                                                    (uint*)hba, W1t, W2t, gcur);
    k_bucket_scatter<<<(N_EDGES + P1_EDGES - 1) / P1_EDGES, 256, 0, stream>>>(
        srcs, dsts, ea2, gcur, tmp);
    k_bucket_sort<<<NBUCK, 256, 0, stream>>>(tmp, gcur, off, rec);

    const int cblocks = N_NODES / TILE;  // 3125, always-full tiles
    // conv1: read hba -> write hbb (bf16 only)
    conv_fused<<<cblocks, 256, 0, stream>>>(off, rec, W_e, b_e,
                                            (const uint4*)hba, W1t, W2t, b1, b2,
                                            nullptr, hbb, 1);
    // conv2: read hbb -> write final f32 out
    conv_fused<<<cblocks, 256, 0, stream>>>(off, rec, W_e, b_e,
                                            (const uint4*)hbb, W1t, W2t, b1, b2,
                                            h, nullptr, 0);
  } else {
    // Fallback: atomic scatter path
    float* agg = (float*)d_ws;
    const size_t agg_bytes = (size_t)N_NODES * HIDDEN * sizeof(float);

    node_init_f32<<<2048, 256, 0, stream>>>(x, W_in, b_in, h);

    hipMemsetAsync(agg, 0, agg_bytes, stream);
    edge_scatter_kernel<<<4096, 256, 0, stream>>>(ei, ea, W_e, b_e, h, agg);
    mlp_f32_kernel<true><<<N_NODES / 32, 256, 0, stream>>>(h, agg, W1, b1, W2, b2, h);

    hipMemsetAsync(agg, 0, agg_bytes, stream);
    edge_scatter_kernel<<<4096, 256, 0, stream>>>(ei, ea, W_e, b_e, h, agg);
    mlp_f32_kernel<false><<<N_NODES / 32, 256, 0, stream>>>(h, agg, W1, b1, W2, b2, h);
  }
}

// Round 11
// 275.715 us; speedup vs baseline: 1.0683x; 1.0683x over previous
//
#include <hip/hip_runtime.h>

#define N_NODES 100000
#define N_EDGES 1600000
#define NODE_DIM 24
#define HIDDEN 128
#define BSHIFT 9     // 512 nodes per bucket
#define NBUCK 196    // ceil(100000/512)
#define BCAP 10240   // per-bucket tmp capacity (mean 8163, +23 sigma)
#define P1_EDGES 2048
#define TILE 32      // nodes per conv block (100000 % 32 == 0)
#define LREC 1024    // staged CSR records per block (mean 512, +22 sigma)
#define NI_BLOCKS 2048

typedef __attribute__((ext_vector_type(8))) short bf16x8;
typedef __attribute__((ext_vector_type(4))) float f32x4;

template <int N> struct IC { static constexpr int value = N; };

__device__ __forceinline__ ushort f2bf(float f) {
  uint u = __builtin_bit_cast(uint, f);
  u += 0x7fffu + ((u >> 16) & 1u);  // RTNE
  return (ushort)(u >> 16);
}
__device__ __forceinline__ float bflo(uint v) { return __builtin_bit_cast(float, v << 16); }
__device__ __forceinline__ float bfhi(uint v) { return __builtin_bit_cast(float, v & 0xffff0000u); }

// ---------------------------------------------------------------------------
// prep: blocks [0,NI_BLOCKS): h0 = x@W_in+b_in -> bf16 table (dword stores)
//       blocks [NI_BLOCKS, NI_BLOCKS+64): W1t/W2t[n][k] = bf16(W[k][n])
//       block NI_BLOCKS+64: zero gcur
// ---------------------------------------------------------------------------
__global__ __launch_bounds__(256) void prep_kernel(
    const float* __restrict__ x, const float* __restrict__ W_in,
    const float* __restrict__ b_in, const float* __restrict__ W1,
    const float* __restrict__ W2, uint* __restrict__ hb32,
    ushort* __restrict__ W1t, ushort* __restrict__ W2t,
    int* __restrict__ gcur) {
  if (blockIdx.x >= NI_BLOCKS) {
    const int bx = blockIdx.x - NI_BLOCKS;
    if (bx >= 64) {  // gcur zeroing
      if (threadIdx.x < NBUCK) gcur[threadIdx.x] = 0;
      return;
    }
    const int i = bx * 256 + threadIdx.x;  // weight transpose+cast
    if (i < HIDDEN * HIDDEN) {
      const int k = i >> 7, n = i & 127;
      W1t[n * HIDDEN + k] = f2bf(W1[k * HIDDEN + n]);
      W2t[n * HIDDEN + k] = f2bf(W2[k * HIDDEN + n]);
    }
    return;
  }
  __shared__ float w_lds[NODE_DIM * HIDDEN];
  __shared__ float b_lds[HIDDEN];
  for (int i = threadIdx.x; i < NODE_DIM * HIDDEN; i += 256) w_lds[i] = W_in[i];
  if (threadIdx.x < HIDDEN) b_lds[threadIdx.x] = b_in[threadIdx.x];
  __syncthreads();
  const int l = threadIdx.x & 63;
  const int g = threadIdx.x >> 6;
  const int j0 = l * 2;
  for (int n = blockIdx.x * 4 + g; n < N_NODES; n += NI_BLOCKS * 4) {
    float a0 = b_lds[j0], a1 = b_lds[j0 + 1];
    const float* xr = x + (size_t)n * NODE_DIM;
#pragma unroll
    for (int d = 0; d < NODE_DIM; ++d) {
      const float xv = xr[d];
      a0 = fmaf(xv, w_lds[d * HIDDEN + j0], a0);
      a1 = fmaf(xv, w_lds[d * HIDDEN + j0 + 1], a1);
    }
    hb32[(size_t)n * 64 + l] = (uint)f2bf(a0) | ((uint)f2bf(a1) << 16);
  }
}

// ---------------------------------------------------------------------------
// Phase 1: bucket scatter into fixed-capacity per-bucket regions.
// ---------------------------------------------------------------------------
__global__ __launch_bounds__(256) void k_bucket_scatter(
    const int* __restrict__ srcs, const int* __restrict__ dsts,
    const float2* __restrict__ ea2, int* __restrict__ gcur,
    uint2* __restrict__ tmp) {
  __shared__ int hist[256];
  __shared__ int sc[256];
  __shared__ int lofs[256];
  __shared__ int base[256];
  __shared__ int cur2[256];
  __shared__ uint2 stage[P1_EDGES];
  __shared__ uchar stage_b[P1_EDGES];
  const int t = threadIdx.x;
  const int e0 = blockIdx.x * P1_EDGES;

  hist[t] = 0;
  cur2[t] = 0;
  __syncthreads();

  uint rw0[8], rw1[8];
  int rb[8];
#pragma unroll
  for (int i = 0; i < 8; ++i) {
    const int e = e0 + t + i * 256;
    if (e < N_EDGES) {
      const int s = srcs[e];
      const int d = dsts[e];
      const float2 a = ea2[e];
      const int b = d >> BSHIFT;
      rb[i] = b;
      rw0[i] = (uint)s | ((uint)(d & 511) << 20);
      rw1[i] = (uint)f2bf(a.x) | ((uint)f2bf(a.y) << 16);
      atomicAdd(&hist[b], 1);
    } else {
      rb[i] = -1;
    }
  }
  __syncthreads();

  int v = hist[t];
  sc[t] = v;
  __syncthreads();
  for (int d = 1; d < 256; d <<= 1) {
    int x = (t >= d) ? sc[t - d] : 0;
    __syncthreads();
    sc[t] += x;
    __syncthreads();
  }
  lofs[t] = sc[t] - v;
  base[t] = (t < NBUCK && v > 0) ? atomicAdd(&gcur[t], v) : 0;
  __syncthreads();

#pragma unroll
  for (int i = 0; i < 8; ++i) {
    if (rb[i] >= 0) {
      const int l = atomicAdd(&cur2[rb[i]], 1);
      const int slot = lofs[rb[i]] + l;
      stage[slot] = make_uint2(rw0[i], rw1[i]);
      stage_b[slot] = (uchar)rb[i];
    }
  }
  __syncthreads();

  const int total = (N_EDGES - e0 < P1_EDGES) ? (N_EDGES - e0) : P1_EDGES;
  for (int s = t; s < total; s += 256) {
    const int b = stage_b[s];
    const int idx = base[b] + (s - lofs[b]);
    if (idx < BCAP) tmp[(size_t)b * BCAP + idx] = stage[s];
  }
}

// ---------------------------------------------------------------------------
// Phase 2: per-bucket. Redundant in-block scan of the 196 bucket counts,
// local histogram + scan -> off[], counting sort -> rec.
// ---------------------------------------------------------------------------
__global__ __launch_bounds__(256) void k_bucket_sort(
    const uint2* __restrict__ tmp, const int* __restrict__ gcur,
    int* __restrict__ off, uint2* __restrict__ rec) {
  __shared__ int gsc[256];
  __shared__ int lcnt[512];
  __shared__ int lofs[512];
  __shared__ int lcur[512];
  __shared__ int psc[256];
  const int t = threadIdx.x;
  const int b = blockIdx.x;
  const int nb0 = b << BSHIFT;
  const uint2* __restrict__ btmp = tmp + (size_t)b * BCAP;

  const int gv = (t < NBUCK) ? gcur[t] : 0;
  gsc[t] = gv;
  lcnt[t] = 0;
  lcnt[t + 256] = 0;
  __syncthreads();
  for (int d = 1; d < 256; d <<= 1) {
    int x = (t >= d) ? gsc[t - d] : 0;
    __syncthreads();
    gsc[t] += x;
    __syncthreads();
  }
  const int rawcnt = gcur[b];
  const int base = gsc[b] - rawcnt;  // exclusive prefix
  int cnt = rawcnt;
  if (cnt > BCAP) cnt = BCAP;
  if (b == 0 && t == 0) off[N_NODES] = N_EDGES;

  for (int s = t; s < cnt; s += 256) {
    atomicAdd(&lcnt[(btmp[s].x >> 20) & 511], 1);
  }
  __syncthreads();
  const int a0 = lcnt[2 * t], a1 = lcnt[2 * t + 1];
  const int p = a0 + a1;
  psc[t] = p;
  __syncthreads();
  for (int d = 1; d < 256; d <<= 1) {
    int x = (t >= d) ? psc[t - d] : 0;
    __syncthreads();
    psc[t] += x;
    __syncthreads();
  }
  const int ep = psc[t] - p;
  lofs[2 * t] = ep;
  lofs[2 * t + 1] = ep + a0;
  lcur[2 * t] = ep;
  lcur[2 * t + 1] = ep + a0;
  __syncthreads();
  for (int i = t; i < 512; i += 256) {
    const int n = nb0 + i;
    if (n < N_NODES) off[n] = base + lofs[i];
  }
  for (int s = t; s < cnt; s += 256) {
    const uint2 r = btmp[s];
    const int dl = (r.x >> 20) & 511;
    const int pp = atomicAdd(&lcur[dl], 1);
    rec[base + pp] = make_uint2(r.x & 0xFFFFFu, r.y);
  }
}

// ---------------------------------------------------------------------------
// Fused conv, TILE=32 (3125 blocks). Gather: 4 groups of 16 lanes, one 256B
// row per group-load; 2 chunks (2 independent row loads) in flight — the
// empirically optimal ILP x occupancy point (R8: 56 VGPR, no spills, 98us;
// deeper ILP or forced occupancy both regressed). shfl_xor reduce; cvt_pk
// pack; MFMA 2-layer MLP on the 32-row tile.
// ---------------------------------------------------------------------------
__global__ __launch_bounds__(256) void conv_fused(
    const int* __restrict__ off, const uint2* __restrict__ rec,
    const float* __restrict__ W_e, const float* __restrict__ b_e,
    const uint4* __restrict__ hb4, const ushort* __restrict__ W1t,
    const ushort* __restrict__ W2t, const float* __restrict__ bias1,
    const float* __restrict__ bias2, float* __restrict__ outf,
    ushort* __restrict__ outb, const int relu_out) {
  __shared__ short zs[TILE][136];
  __shared__ uint2 lrec[LREC];
  __shared__ int loff[TILE + 1];
  const int tid = threadIdx.x;
  const int lane = tid & 63;
  const int wave = tid >> 6;
  const int l15 = lane & 15;
  const int grp = lane >> 4;  // 0..3: which edge of the chunk
  const int n0 = blockIdx.x * TILE;

  if (tid <= TILE) loff[tid] = off[n0 + tid];
  const int rbase = off[n0];
  const int rend = off[n0 + TILE];
  const int rcnt = rend - rbase;
  const bool staged = (rcnt <= LREC);
  if (staged) {
    for (int i = tid; i < rcnt; i += 256) lrec[i] = rec[rbase + i];
  }

  // this lane's feature octet weights
  const int j0 = l15 * 8;
  float we0[8], we1[8], beq[8];
#pragma unroll
  for (int k = 0; k < 8; ++k) {
    we0[k] = W_e[j0 + k];
    we1[k] = W_e[HIDDEN + j0 + k];
    beq[k] = b_e[j0 + k];
  }
  __syncthreads();

  // ---- gather phase ----
  {
    auto gather = [&](auto readrec) {
      for (int i = 0; i < 8; ++i) {
        const int n = n0 + wave * 8 + i;
        float acc[8];
#pragma unroll
        for (int k = 0; k < 8; ++k) acc[k] = 0.f;
        const int o = loff[wave * 8 + i] - rbase;
        const int dn = loff[wave * 8 + i + 1] - loff[wave * 8 + i];
        const int nfull = dn >> 2;

        auto edge_math = [&](uint2 r, uint4 hv) {
          const float ex = bflo(r.y), ey = bfhi(r.y);
          const uint hw[4] = {hv.x, hv.y, hv.z, hv.w};
#pragma unroll
          for (int k = 0; k < 4; ++k) {
            const float c0 = fmaf(ex, we0[2 * k], fmaf(ey, we1[2 * k], beq[2 * k]));
            const float c1 = fmaf(ex, we0[2 * k + 1], fmaf(ey, we1[2 * k + 1], beq[2 * k + 1]));
            acc[2 * k] += fmaxf(bflo(hw[k]) + c0, 0.f);
            acc[2 * k + 1] += fmaxf(bfhi(hw[k]) + c1, 0.f);
          }
        };
        auto do_chunks = [&](int obase, auto cn) {
          constexpr int C = decltype(cn)::value;
          uint2 r[C];
          uint4 hv[C];
#pragma unroll
          for (int q = 0; q < C; ++q) r[q] = readrec(obase + q * 4 + grp);
#pragma unroll
          for (int q = 0; q < C; ++q) hv[q] = hb4[(size_t)r[q].x * 16 + l15];
#pragma unroll
          for (int q = 0; q < C; ++q) edge_math(r[q], hv[q]);
        };

        int c = 0;
        for (; c + 2 <= nfull; c += 2) do_chunks(o + c * 4, IC<2>{});
        if (c < nfull) { do_chunks(o + c * 4, IC<1>{}); c += 1; }
        const int ntail = dn & 3;
        if (grp < ntail) {  // 16-lane-uniform predicate
          const uint2 r0 = readrec(o + nfull * 4 + grp);
          const uint4 hv0 = hb4[(size_t)r0.x * 16 + l15];
          edge_math(r0, hv0);
        }

        // cross-group reduce (4 partials -> replicated total)
#pragma unroll
        for (int k = 0; k < 8; ++k) {
          float v = acc[k];
          v += __shfl_xor(v, 16, 64);
          v += __shfl_xor(v, 32, 64);
          acc[k] = v;
        }
        // self term (no relu, no edge coef)
        const uint4 hs = hb4[(size_t)n * 16 + l15];
        acc[0] += bflo(hs.x); acc[1] += bfhi(hs.x);
        acc[2] += bflo(hs.y); acc[3] += bfhi(hs.y);
        acc[4] += bflo(hs.z); acc[5] += bfhi(hs.z);
        acc[6] += bflo(hs.w); acc[7] += bfhi(hs.w);

        uint p0, p1, p2, p3;
        asm("v_cvt_pk_bf16_f32 %0, %1, %2" : "=v"(p0) : "v"(acc[0]), "v"(acc[1]));
        asm("v_cvt_pk_bf16_f32 %0, %1, %2" : "=v"(p1) : "v"(acc[2]), "v"(acc[3]));
        asm("v_cvt_pk_bf16_f32 %0, %1, %2" : "=v"(p2) : "v"(acc[4]), "v"(acc[5]));
        asm("v_cvt_pk_bf16_f32 %0, %1, %2" : "=v"(p3) : "v"(acc[6]), "v"(acc[7]));
        if (grp == 0) {
          *(uint4*)&zs[wave * 8 + i][l15 * 8] = make_uint4(p0, p1, p2, p3);
        }
      }
    };
    if (staged) {
      gather([&](int i) -> uint2 { return lrec[i]; });
    } else {
      gather([&](int i) -> uint2 { return rec[rbase + i]; });
    }
  }
  __syncthreads();

  // ---- MLP phase (MFMA), 32 rows; z/t aliased in zs ----
  const int kq = grp;
  const int colbase = wave * 32;
  const int c0 = colbase + l15, c1 = colbase + 16 + l15;

  f32x4 acc[2][2];
  {
    const float bb0 = bias1[c0], bb1 = bias1[c1];
#pragma unroll
    for (int mt = 0; mt < 2; ++mt) {
      acc[mt][0] = (f32x4){bb0, bb0, bb0, bb0};
      acc[mt][1] = (f32x4){bb1, bb1, bb1, bb1};
    }
  }
#pragma unroll
  for (int kt = 0; kt < 4; ++kt) {
    const int kk = kt * 32 + kq * 8;
    const bf16x8 bf0 = *(const bf16x8*)&W1t[(size_t)c0 * HIDDEN + kk];
    const bf16x8 bf1 = *(const bf16x8*)&W1t[(size_t)c1 * HIDDEN + kk];
#pragma unroll
    for (int mt = 0; mt < 2; ++mt) {
      const bf16x8 a = *(const bf16x8*)&zs[mt * 16 + l15][kk];
      acc[mt][0] = __builtin_amdgcn_mfma_f32_16x16x32_bf16(a, bf0, acc[mt][0], 0, 0, 0);
      acc[mt][1] = __builtin_amdgcn_mfma_f32_16x16x32_bf16(a, bf1, acc[mt][1], 0, 0, 0);
    }
  }
  __syncthreads();  // all layer-1 reads of zs complete
#pragma unroll
  for (int mt = 0; mt < 2; ++mt)
#pragma unroll
    for (int nt = 0; nt < 2; ++nt)
#pragma unroll
      for (int r = 0; r < 4; ++r) {
        const int row = mt * 16 + kq * 4 + r;
        const int col = colbase + nt * 16 + l15;
        float v = acc[mt][nt][r];
        zs[row][col] = (short)f2bf(v > 0.f ? v : 0.f);
      }
  __syncthreads();

  {
    const float bb0 = bias2[c0], bb1 = bias2[c1];
#pragma unroll
    for (int mt = 0; mt < 2; ++mt) {
      acc[mt][0] = (f32x4){bb0, bb0, bb0, bb0};
      acc[mt][1] = (f32x4){bb1, bb1, bb1, bb1};
    }
  }
#pragma unroll
  for (int kt = 0; kt < 4; ++kt) {
    const int kk = kt * 32 + kq * 8;
    const bf16x8 bf0 = *(const bf16x8*)&W2t[(size_t)c0 * HIDDEN + kk];
    const bf16x8 bf1 = *(const bf16x8*)&W2t[(size_t)c1 * HIDDEN + kk];
#pragma unroll
    for (int mt = 0; mt < 2; ++mt) {
      const bf16x8 a = *(const bf16x8*)&zs[mt * 16 + l15][kk];
      acc[mt][0] = __builtin_amdgcn_mfma_f32_16x16x32_bf16(a, bf0, acc[mt][0], 0, 0, 0);
      acc[mt][1] = __builtin_amdgcn_mfma_f32_16x16x32_bf16(a, bf1, acc[mt][1], 0, 0, 0);
    }
  }
#pragma unroll
  for (int mt = 0; mt < 2; ++mt)
#pragma unroll
    for (int nt = 0; nt < 2; ++nt)
#pragma unroll
      for (int r = 0; r < 4; ++r) {
        const int row = mt * 16 + kq * 4 + r;
        const int col = colbase + nt * 16 + l15;
        float v = acc[mt][nt][r];
        if (relu_out) v = v > 0.f ? v : 0.f;
        if (outf) outf[(size_t)(n0 + row) * HIDDEN + col] = v;
        if (outb) outb[(size_t)(n0 + row) * HIDDEN + col] = f2bf(v);
      }
}

// ---------------------------------------------------------------------------
// Fallback path (atomic scatter + f32 MLP), used only if ws too small
// ---------------------------------------------------------------------------
__global__ __launch_bounds__(256) void node_init_f32(
    const float* __restrict__ x, const float* __restrict__ W_in,
    const float* __restrict__ b_in, float* __restrict__ h) {
  __shared__ float w_lds[NODE_DIM * HIDDEN];
  __shared__ float b_lds[HIDDEN];
  for (int i = threadIdx.x; i < NODE_DIM * HIDDEN; i += 256) w_lds[i] = W_in[i];
  if (threadIdx.x < HIDDEN) b_lds[threadIdx.x] = b_in[threadIdx.x];
  __syncthreads();
  const int j = threadIdx.x & 127;
  const int g = threadIdx.x >> 7;
  for (int n = blockIdx.x * 2 + g; n < N_NODES; n += gridDim.x * 2) {
    float acc = b_lds[j];
    const float* xr = x + (size_t)n * NODE_DIM;
#pragma unroll
    for (int d = 0; d < NODE_DIM; ++d) acc = fmaf(xr[d], w_lds[d * HIDDEN + j], acc);
    h[(size_t)n * HIDDEN + j] = acc;
  }
}

__global__ __launch_bounds__(256) void edge_scatter_kernel(
    const int* __restrict__ ei, const float* __restrict__ ea,
    const float* __restrict__ W_e, const float* __restrict__ b_e,
    const float* __restrict__ h, float* __restrict__ agg) {
  const int j = threadIdx.x & 127;
  const int g = threadIdx.x >> 7;
  const float we0 = W_e[j];
  const float we1 = W_e[HIDDEN + j];
  const float be = b_e[j];
  const int* __restrict__ srcs = ei;
  const int* __restrict__ dsts = ei + N_EDGES;
  const float2* __restrict__ ea2 = (const float2*)ea;
  for (int e = blockIdx.x * 2 + g; e < N_EDGES; e += gridDim.x * 2) {
    const int s = srcs[e];
    const int d = dsts[e];
    const float2 a = ea2[e];
    float m = h[(size_t)s * HIDDEN + j] + fmaf(a.x, we0, fmaf(a.y, we1, be));
    m = m > 0.f ? m : 0.f;
    unsafeAtomicAdd(&agg[(size_t)d * HIDDEN + j], m);
  }
}

template <bool RELU_OUT>
__global__ __launch_bounds__(256) void mlp_f32_kernel(
    const float* __restrict__ zbuf, const float* __restrict__ agg,
    const float* __restrict__ W1, const float* __restrict__ b1,
    const float* __restrict__ W2, const float* __restrict__ b2,
    float* __restrict__ out) {
  const int NB = 32;
  const int NT = 16;
  __shared__ float zs[NB][HIDDEN];
  __shared__ float ts[NB][HIDDEN];
  const int j = threadIdx.x & 127;
  const int g = threadIdx.x >> 7;
  const int n0 = blockIdx.x * NB;

#pragma unroll
  for (int n = 0; n < NT; ++n) {
    const int nn = g * NT + n;
    zs[nn][j] = zbuf[(size_t)(n0 + nn) * HIDDEN + j] + agg[(size_t)(n0 + nn) * HIDDEN + j];
  }
  __syncthreads();

  float acc[NT];
  const float b1j = b1[j];
#pragma unroll
  for (int n = 0; n < NT; ++n) acc[n] = b1j;
  for (int k = 0; k < HIDDEN; k += 4) {
    const float w0 = W1[(k + 0) * HIDDEN + j];
    const float w1 = W1[(k + 1) * HIDDEN + j];
    const float w2 = W1[(k + 2) * HIDDEN + j];
    const float w3 = W1[(k + 3) * HIDDEN + j];
#pragma unroll
    for (int n = 0; n < NT; ++n) {
      const float4 z = *reinterpret_cast<const float4*>(&zs[g * NT + n][k]);
      acc[n] = fmaf(z.x, w0, acc[n]);
      acc[n] = fmaf(z.y, w1, acc[n]);
      acc[n] = fmaf(z.z, w2, acc[n]);
      acc[n] = fmaf(z.w, w3, acc[n]);
    }
  }
#pragma unroll
  for (int n = 0; n < NT; ++n) ts[g * NT + n][j] = acc[n] > 0.f ? acc[n] : 0.f;
  __syncthreads();

  const float b2j = b2[j];
#pragma unroll
  for (int n = 0; n < NT; ++n) acc[n] = b2j;
  for (int k = 0; k < HIDDEN; k += 4) {
    const float w0 = W2[(k + 0) * HIDDEN + j];
    const float w1 = W2[(k + 1) * HIDDEN + j];
    const float w2 = W2[(k + 2) * HIDDEN + j];
    const float w3 = W2[(k + 3) * HIDDEN + j];
#pragma unroll
    for (int n = 0; n < NT; ++n) {
      const float4 z = *reinterpret_cast<const float4*>(&ts[g * NT + n][k]);
      acc[n] = fmaf(z.x, w0, acc[n]);
      acc[n] = fmaf(z.y, w1, acc[n]);
      acc[n] = fmaf(z.z, w2, acc[n]);
      acc[n] = fmaf(z.w, w3, acc[n]);
    }
  }
#pragma unroll
  for (int n = 0; n < NT; ++n) {
    float v = acc[n];
    if (RELU_OUT) v = v > 0.f ? v : 0.f;
    out[(size_t)(n0 + g * NT + n) * HIDDEN + j] = v;
  }
}

extern "C" void kernel_launch(void* const* d_in, const int* in_sizes, int n_in,
                              void* d_out, int out_size, void* d_ws, size_t ws_size,
                              hipStream_t stream) {
  const float* x    = (const float*)d_in[0];
  const int*   ei   = (const int*)d_in[1];
  const float* ea   = (const float*)d_in[2];
  const float* W_in = (const float*)d_in[3];
  const float* b_in = (const float*)d_in[4];
  const float* W_e  = (const float*)d_in[5];
  const float* b_e  = (const float*)d_in[6];
  const float* W1   = (const float*)d_in[7];
  const float* b1   = (const float*)d_in[8];
  const float* W2   = (const float*)d_in[9];
  const float* b2   = (const float*)d_in[10];

  const int* srcs = ei;
  const int* dsts = ei + N_EDGES;
  const float2* ea2 = (const float2*)ea;

  float* h = (float*)d_out;  // final f32 output
  char* ws = (char*)d_ws;

  // ws layout. tmp (phase-1 buckets) overlays hb_b (tmp dead after sort).
  const size_t OFF_OFF  = 0;                       // (N+1)*4 = 400004
  const size_t GCUR_OFF = 402432;                  // 784
  const size_t WT1_OFF  = 410624;                  // 32768
  const size_t WT2_OFF  = 443392;                  // 32768
  const size_t REC_OFF  = 1048576;                 // 12.8 MB final CSR records
  const size_t HBA_OFF  = REC_OFF + 12800000;      // 25.6 MB bf16 h (table A)
  const size_t TMP_OFF  = HBA_OFF + 25600000;      // 16.06 MB bucket regions
  const size_t HBB_OFF  = TMP_OFF;                 // 25.6 MB bf16 h (table B)
  const size_t need = HBB_OFF + 25600000;          // ~65.0 MB

  if (ws_size >= need) {
    int* off     = (int*)(ws + OFF_OFF);
    int* gcur    = (int*)(ws + GCUR_OFF);
    ushort* W1t  = (ushort*)(ws + WT1_OFF);
    ushort* W2t  = (ushort*)(ws + WT2_OFF);
    uint2* rec   = (uint2*)(ws + REC_OFF);
    ushort* hba  = (ushort*)(ws + HBA_OFF);
    uint2* tmp   = (uint2*)(ws + TMP_OFF);
    ushort* hbb  = (ushort*)(ws + HBB_OFF);

    // h0 -> bf16 table; W1t/W2t transpose; gcur zero (merged kernel)
    prep_kernel<<<NI_BLOCKS + 65, 256, 0, stream>>>(x, W_in, b_in, W1, W2,
                                                    (uint*)hba, W1t, W2t, gcur);
    k_bucket_scatter<<<(N_EDGES + P1_EDGES - 1) / P1_EDGES, 256, 0, stream>>>(
        srcs, dsts, ea2, gcur, tmp);
    k_bucket_sort<<<NBUCK, 256, 0, stream>>>(tmp, gcur, off, rec);

    const int cblocks = N_NODES / TILE;  // 3125, always-full tiles
    // conv1: read hba -> write hbb (bf16 only)
    conv_fused<<<cblocks, 256, 0, stream>>>(off, rec, W_e, b_e,
                                            (const uint4*)hba, W1t, W2t, b1, b2,
                                            nullptr, hbb, 1);
    // conv2: read hbb -> write final f32 out
    conv_fused<<<cblocks, 256, 0, stream>>>(off, rec, W_e, b_e,
                                            (const uint4*)hbb, W1t, W2t, b1, b2,
                                            h, nullptr, 0);
  } else {
    // Fallback: atomic scatter path
    float* agg = (float*)d_ws;
    const size_t agg_bytes = (size_t)N_NODES * HIDDEN * sizeof(float);

    node_init_f32<<<2048, 256, 0, stream>>>(x, W_in, b_in, h);

    hipMemsetAsync(agg, 0, agg_bytes, stream);
    edge_scatter_kernel<<<4096, 256, 0, stream>>>(ei, ea, W_e, b_e, h, agg);
    mlp_f32_kernel<true><<<N_NODES / 32, 256, 0, stream>>>(h, agg, W1, b1, W2, b2, h);

    hipMemsetAsync(agg, 0, agg_bytes, stream);
    edge_scatter_kernel<<<4096, 256, 0, stream>>>(ei, ea, W_e, b_e, h, agg);
    mlp_f32_kernel<false><<<N_NODES / 32, 256, 0, stream>>>(h, agg, W1, b1, W2, b2, h);
  }
}